// Round 8
// baseline (222.513 us; speedup 1.0000x reference)
//
#include <hip/hip_runtime.h>
#include <math.h>

#define NEG_SLOPE 0.2f
#define NPAD 50176            // node capacity (multiple of 512)
#define NW8  (NPAD / 4)       // packed u32 cells (4 x u8 counts)
#define NCHUNK 256            // edge chunks == k_hist blocks

// ---- phase 1: per-chunk histogram via LDS atomics (4x u8 packed); emits rank ----
__global__ __launch_bounds__(1024) void k_hist(const int* __restrict__ dst,
                                               unsigned int* __restrict__ histw,
                                               unsigned char* __restrict__ rank,
                                               int e, int es) {
    extern __shared__ unsigned int lcnt[];  // NW8 u32 = 50176 B
    int t = threadIdx.x;
    for (int w = t; w < NW8; w += 1024) lcnt[w] = 0u;
    __syncthreads();
    int beg = blockIdx.x * es;
    int end = min(beg + es, e);
    for (int i = beg + t; i < end; i += 1024) {
        int d = dst[i];
        int sh = (d & 3) << 3;
        unsigned int old = atomicAdd(&lcnt[d >> 2], 1u << sh);
        rank[i] = (unsigned char)((old >> sh) & 0xffu);
    }
    __syncthreads();
    unsigned int* out = histw + (size_t)blockIdx.x * NW8;
    for (int w = t; w < NW8; w += 1024) out[w] = lcnt[w];
}

// ---- phase 2: per-node exclusive scan over chunks (in place, u8), deg/dinv/bsum ----
__global__ __launch_bounds__(256) void k_chscan(unsigned char* __restrict__ hist8,
                                                float* __restrict__ dinv,
                                                unsigned short* __restrict__ deg16,
                                                int* __restrict__ bsum, int n) {
    int t = threadIdx.x;
    int i = blockIdx.x * 256 + t;          // grid covers NPAD exactly
    unsigned char* p = hist8 + i;
    unsigned int run = 0;
    for (int c = 0; c < NCHUNK; c += 8) {
        size_t b = (size_t)c * NPAD;
        unsigned char v0 = p[b];
        unsigned char v1 = p[b + (size_t)1 * NPAD];
        unsigned char v2 = p[b + (size_t)2 * NPAD];
        unsigned char v3 = p[b + (size_t)3 * NPAD];
        unsigned char v4 = p[b + (size_t)4 * NPAD];
        unsigned char v5 = p[b + (size_t)5 * NPAD];
        unsigned char v6 = p[b + (size_t)6 * NPAD];
        unsigned char v7 = p[b + (size_t)7 * NPAD];
        unsigned int e0 = run;
        unsigned int e1 = e0 + v0;
        unsigned int e2 = e1 + v1;
        unsigned int e3 = e2 + v2;
        unsigned int e4 = e3 + v3;
        unsigned int e5 = e4 + v4;
        unsigned int e6 = e5 + v5;
        unsigned int e7 = e6 + v6;
        run = e7 + v7;
        p[b] = (unsigned char)e0;
        p[b + (size_t)1 * NPAD] = (unsigned char)e1;
        p[b + (size_t)2 * NPAD] = (unsigned char)e2;
        p[b + (size_t)3 * NPAD] = (unsigned char)e3;
        p[b + (size_t)4 * NPAD] = (unsigned char)e4;
        p[b + (size_t)5 * NPAD] = (unsigned char)e5;
        p[b + (size_t)6 * NPAD] = (unsigned char)e6;
        p[b + (size_t)7 * NPAD] = (unsigned char)e7;
    }
    int deg = (int)run;
    if (i < n) dinv[i] = rsqrtf((float)(deg + 1));  // +1 self-loop
    deg16[i] = (unsigned short)deg;                 // zero beyond n
    int s = deg;
    for (int d = 1; d < 64; d <<= 1) s += __shfl_down(s, d);
    __shared__ int ws[4];
    if ((t & 63) == 0) ws[t >> 6] = s;
    __syncthreads();
    if (t == 0) bsum[blockIdx.x] = ws[0] + ws[1] + ws[2] + ws[3];
}

// ---- phase 3: rowptr = global exclusive scan (block prefix of bsum + local scan) ----
__global__ __launch_bounds__(256) void k_scan3(const unsigned short* __restrict__ deg16,
                                               const int* __restrict__ bsum,
                                               int* __restrict__ rowptr, int n, int nb) {
    __shared__ int ls[256];
    __shared__ int wo[4];
    int t = threadIdx.x;
    int bid = blockIdx.x;
    int bv = (t < bid && t < nb) ? bsum[t] : 0;
    for (int d = 1; d < 64; d <<= 1) bv += __shfl_down(bv, d);
    if ((t & 63) == 0) wo[t >> 6] = bv;
    __syncthreads();
    int boff = wo[0] + wo[1] + wo[2] + wo[3];
    int i = bid * 256 + t;
    int v = (i < n) ? (int)deg16[i] : 0;
    ls[t] = v;
    __syncthreads();
    for (int d = 1; d < 256; d <<= 1) {
        int u = (t >= d) ? ls[t - d] : 0;
        __syncthreads();
        ls[t] += u;
        __syncthreads();
    }
    int excl = ls[t] - v + boff;
    if (i < n) rowptr[i] = excl;
    if (i == n - 1) rowptr[n] = excl + v;
}

// ---- phase 4: place (no atomics) ----
__global__ void k_place(const int* __restrict__ src, const int* __restrict__ dst,
                        const int* __restrict__ rowptr, const unsigned char* __restrict__ rank,
                        const unsigned char* __restrict__ choff,
                        int* __restrict__ perm, int e, int es) {
    int i = blockIdx.x * 256 + threadIdx.x;
    if (i >= e) return;
    int d = dst[i];
    unsigned int c = (unsigned int)i / (unsigned int)es;
    int slot = rowptr[d] + (int)choff[(size_t)c * NPAD + d] + (int)rank[i];
    perm[slot] = src[i];
}

// ---------------- fused layer: gather (wave/node, lane=channel) + W-GEMM + bias + act ----
// MODE 0: input is raw x -> fold dinv[src] per edge; MODE 1: input already pre-scaled by dinv.
// Output is stored pre-scaled by dinv[v] for the next layer's gather.
template <int MODE>
__global__ __launch_bounds__(256) void k_layer64(
        const float* __restrict__ h, const float* __restrict__ dinv,
        const int* __restrict__ rowptr, const int* __restrict__ perm,
        const float* __restrict__ W, const float* __restrict__ b,
        float* __restrict__ out, int n) {
    __shared__ float Ws[64 * 64];
    int t = threadIdx.x;
    {
        const float4* W4 = (const float4*)W;
        float4* Ws4 = (float4*)Ws;
#pragma unroll
        for (int i = 0; i < 4; ++i) Ws4[t + 256 * i] = W4[t + 256 * i];
    }
    __syncthreads();
    int v = blockIdx.x * 4 + (t >> 6);
    if (v >= n) return;
    v = __builtin_amdgcn_readfirstlane(v);  // SGPR: perm/rowptr/dinv become scalar loads
    int lane = t & 63;
    const float* hl = h + lane;
    float dv = dinv[v];
    float acc = hl[(size_t)v * 64];
    if (MODE == 0) acc *= dv;               // self term: dinv[v]*x[v]
    int e = rowptr[v], end = rowptr[v + 1];
#define LOADK(j) int s##j = perm[e + j]; float x##j = hl[(size_t)s##j * 64]; \
                 if (MODE == 0) x##j *= dinv[s##j]
    for (; e + 16 <= end; e += 16) {
        LOADK(0); LOADK(1); LOADK(2); LOADK(3);
        LOADK(4); LOADK(5); LOADK(6); LOADK(7);
        LOADK(8); LOADK(9); LOADK(10); LOADK(11);
        LOADK(12); LOADK(13); LOADK(14); LOADK(15);
        acc += (((x0 + x1) + (x2 + x3)) + ((x4 + x5) + (x6 + x7)))
             + (((x8 + x9) + (x10 + x11)) + ((x12 + x13) + (x14 + x15)));
    }
    if (e + 8 <= end) {
        LOADK(0); LOADK(1); LOADK(2); LOADK(3);
        LOADK(4); LOADK(5); LOADK(6); LOADK(7);
        acc += ((x0 + x1) + (x2 + x3)) + ((x4 + x5) + (x6 + x7));
        e += 8;
    }
    if (e + 4 <= end) {
        LOADK(0); LOADK(1); LOADK(2); LOADK(3);
        acc += (x0 + x1) + (x2 + x3);
        e += 4;
    }
    if (e + 2 <= end) {
        LOADK(0); LOADK(1);
        acc += x0 + x1;
        e += 2;
    }
    if (e < end) {
        LOADK(0);
        acc += x0;
    }
#undef LOADK
    acc *= dv;                              // agg = dinv[v] * (self + sum)
    // in-wave GEMM: o[lane] = sum_k agg[k] * W[k][lane] + b[lane]
    float o = b[lane];
#pragma unroll
    for (int k = 0; k < 64; ++k)
        o = fmaf(__shfl(acc, k), Ws[k * 64 + lane], o);
    o = o > 0.0f ? o : o * NEG_SLOPE;       // leaky relu
    out[(size_t)v * 64 + lane] = o * dv;    // pre-scale for next layer
}

// ---------------- fused final layer: gather + W2 (64x4) + bias, no act, raw output ----
__global__ __launch_bounds__(256) void k_layer4(
        const float* __restrict__ h, const float* __restrict__ dinv,
        const int* __restrict__ rowptr, const int* __restrict__ perm,
        const float* __restrict__ W, const float* __restrict__ b,
        float* __restrict__ out, int n) {
    __shared__ float Ws[256];
    int t = threadIdx.x;
    Ws[t] = W[t];
    __syncthreads();
    int v = blockIdx.x * 4 + (t >> 6);
    if (v >= n) return;
    v = __builtin_amdgcn_readfirstlane(v);
    int lane = t & 63;
    const float* hl = h + lane;
    float acc = hl[(size_t)v * 64];
    int e = rowptr[v], end = rowptr[v + 1];
#define LOADK(j) float x##j = hl[(size_t)perm[e + j] * 64]
    for (; e + 16 <= end; e += 16) {
        LOADK(0); LOADK(1); LOADK(2); LOADK(3);
        LOADK(4); LOADK(5); LOADK(6); LOADK(7);
        LOADK(8); LOADK(9); LOADK(10); LOADK(11);
        LOADK(12); LOADK(13); LOADK(14); LOADK(15);
        acc += (((x0 + x1) + (x2 + x3)) + ((x4 + x5) + (x6 + x7)))
             + (((x8 + x9) + (x10 + x11)) + ((x12 + x13) + (x14 + x15)));
    }
    if (e + 8 <= end) {
        LOADK(0); LOADK(1); LOADK(2); LOADK(3);
        LOADK(4); LOADK(5); LOADK(6); LOADK(7);
        acc += ((x0 + x1) + (x2 + x3)) + ((x4 + x5) + (x6 + x7));
        e += 8;
    }
    if (e + 4 <= end) {
        LOADK(0); LOADK(1); LOADK(2); LOADK(3);
        acc += (x0 + x1) + (x2 + x3);
        e += 4;
    }
    if (e + 2 <= end) {
        LOADK(0); LOADK(1);
        acc += x0 + x1;
        e += 2;
    }
    if (e < end) acc += hl[(size_t)perm[e] * 64];
#undef LOADK
    acc *= dinv[v];
    int c = lane & 3;
    float o = b[c];
#pragma unroll
    for (int k = 0; k < 64; ++k)
        o = fmaf(__shfl(acc, k), Ws[k * 4 + c], o);
    if (lane < 4) out[(size_t)v * 4 + lane] = o;
}

extern "C" void kernel_launch(void* const* d_in, const int* in_sizes, int n_in,
                              void* d_out, int out_size, void* d_ws, size_t ws_size,
                              hipStream_t stream) {
    const float* x  = (const float*)d_in[0];
    const int* ei   = (const int*)d_in[1];
    const float* W0 = (const float*)d_in[2];
    const float* b0 = (const float*)d_in[3];
    const float* W1 = (const float*)d_in[4];
    const float* b1 = (const float*)d_in[5];
    const float* W2 = (const float*)d_in[6];
    const float* b2 = (const float*)d_in[7];
    float* out = (float*)d_out;

    const int N = in_sizes[0] / 64;
    const int E = in_sizes[1] / 2;
    const int* src = ei;
    const int* dst = ei + E;
    const int es = (E + NCHUNK - 1) / NCHUNK;   // edges per chunk

    // workspace layout, 256B-aligned slabs
    char* base = (char*)d_ws;
    size_t off = 0;
    auto alloc = [&](size_t bytes) { size_t o = off; off = (off + bytes + 255) & ~(size_t)255; return o; };
    unsigned int*   histw  = (unsigned int*)(base + alloc((size_t)NCHUNK * NPAD));  // u8[C][NPAD]
    unsigned char*  rank   = (unsigned char*)(base + alloc((size_t)E));
    unsigned short* deg16  = (unsigned short*)(base + alloc((size_t)NPAD * 2));
    float*          dinv   = (float*)(base + alloc((size_t)NPAD * 4));
    int*            rowptr = (int*)(base + alloc((size_t)(NPAD + 1) * 4));
    int*            bsum   = (int*)(base + alloc(1024));
    int*            perm   = (int*)(base + alloc((size_t)E * 4));
    float*          bufA   = (float*)(base + alloc((size_t)N * 64 * 4));
    float*          bufB   = (float*)(base + alloc((size_t)N * 64 * 4));

    const int nb_N = (N + 255) / 256;   // 196
    const int nb_E = (E + 255) / 256;
    const int nb_V = (N + 3) / 4;       // 12500 (wave per node, 4/block)

    // ---- CSR build + normalization (no global atomics) ----
    k_hist<<<NCHUNK, 1024, NW8 * sizeof(unsigned int), stream>>>(dst, histw, rank, E, es);
    k_chscan<<<NPAD / 256, 256, 0, stream>>>((unsigned char*)histw, dinv, deg16, bsum, N);
    k_scan3<<<nb_N, 256, 0, stream>>>(deg16, bsum, rowptr, N, nb_N);
    k_place<<<nb_E, 256, 0, stream>>>(src, dst, rowptr, rank, (const unsigned char*)histw, perm, E, es);

    // ---- fused layers ----
    k_layer64<0><<<nb_V, 256, 0, stream>>>(x,    dinv, rowptr, perm, W0, b0, bufB, N);
    k_layer64<1><<<nb_V, 256, 0, stream>>>(bufB, dinv, rowptr, perm, W1, b1, bufA, N);
    k_layer4<<<nb_V, 256, 0, stream>>>(bufA, dinv, rowptr, perm, W2, b2, out, N);
}

// Round 10
// 187.600 us; speedup vs baseline: 1.1861x; 1.1861x over previous
//
#include <hip/hip_runtime.h>
#include <math.h>

#define NEG_SLOPE 0.2f
#define NPAD 50176            // node capacity (multiple of 512)
#define NW8  (NPAD / 4)       // packed u32 cells (4 x u8 counts)
#define NCHUNK 256            // edge chunks == k_hist blocks

// ---- phase 1: per-chunk histogram via LDS atomics (4x u8 packed); emits rank ----
__global__ __launch_bounds__(1024) void k_hist(const int* __restrict__ dst,
                                               unsigned int* __restrict__ histw,
                                               unsigned char* __restrict__ rank,
                                               int e, int es) {
    extern __shared__ unsigned int lcnt[];  // NW8 u32 = 50176 B
    int t = threadIdx.x;
    for (int w = t; w < NW8; w += 1024) lcnt[w] = 0u;
    __syncthreads();
    int beg = blockIdx.x * es;
    int end = min(beg + es, e);
    for (int i = beg + t; i < end; i += 1024) {
        int d = dst[i];
        int sh = (d & 3) << 3;
        unsigned int old = atomicAdd(&lcnt[d >> 2], 1u << sh);
        rank[i] = (unsigned char)((old >> sh) & 0xffu);
    }
    __syncthreads();
    unsigned int* out = histw + (size_t)blockIdx.x * NW8;
    for (int w = t; w < NW8; w += 1024) out[w] = lcnt[w];
}

// ---- phase 2: per-node exclusive scan over chunks (in place, u8), deg/dinv/bsum ----
__global__ __launch_bounds__(256) void k_chscan(unsigned char* __restrict__ hist8,
                                                float* __restrict__ dinv,
                                                unsigned short* __restrict__ deg16,
                                                int* __restrict__ bsum, int n) {
    int t = threadIdx.x;
    int i = blockIdx.x * 256 + t;          // grid covers NPAD exactly
    unsigned char* p = hist8 + i;
    unsigned int run = 0;
    for (int c = 0; c < NCHUNK; c += 8) {
        size_t b = (size_t)c * NPAD;
        unsigned char v0 = p[b];
        unsigned char v1 = p[b + (size_t)1 * NPAD];
        unsigned char v2 = p[b + (size_t)2 * NPAD];
        unsigned char v3 = p[b + (size_t)3 * NPAD];
        unsigned char v4 = p[b + (size_t)4 * NPAD];
        unsigned char v5 = p[b + (size_t)5 * NPAD];
        unsigned char v6 = p[b + (size_t)6 * NPAD];
        unsigned char v7 = p[b + (size_t)7 * NPAD];
        unsigned int e0 = run;
        unsigned int e1 = e0 + v0;
        unsigned int e2 = e1 + v1;
        unsigned int e3 = e2 + v2;
        unsigned int e4 = e3 + v3;
        unsigned int e5 = e4 + v4;
        unsigned int e6 = e5 + v5;
        unsigned int e7 = e6 + v6;
        run = e7 + v7;
        p[b] = (unsigned char)e0;
        p[b + (size_t)1 * NPAD] = (unsigned char)e1;
        p[b + (size_t)2 * NPAD] = (unsigned char)e2;
        p[b + (size_t)3 * NPAD] = (unsigned char)e3;
        p[b + (size_t)4 * NPAD] = (unsigned char)e4;
        p[b + (size_t)5 * NPAD] = (unsigned char)e5;
        p[b + (size_t)6 * NPAD] = (unsigned char)e6;
        p[b + (size_t)7 * NPAD] = (unsigned char)e7;
    }
    int deg = (int)run;
    if (i < n) dinv[i] = rsqrtf((float)(deg + 1));  // +1 self-loop
    deg16[i] = (unsigned short)deg;                 // zero beyond n
    int s = deg;
    for (int d = 1; d < 64; d <<= 1) s += __shfl_down(s, d);
    __shared__ int ws[4];
    if ((t & 63) == 0) ws[t >> 6] = s;
    __syncthreads();
    if (t == 0) bsum[blockIdx.x] = ws[0] + ws[1] + ws[2] + ws[3];
}

// ---- phase 3: rowptr = global exclusive scan (block prefix of bsum + local scan) ----
__global__ __launch_bounds__(256) void k_scan3(const unsigned short* __restrict__ deg16,
                                               const int* __restrict__ bsum,
                                               int* __restrict__ rowptr, int n, int nb) {
    __shared__ int ls[256];
    __shared__ int wo[4];
    int t = threadIdx.x;
    int bid = blockIdx.x;
    int bv = (t < bid && t < nb) ? bsum[t] : 0;
    for (int d = 1; d < 64; d <<= 1) bv += __shfl_down(bv, d);
    if ((t & 63) == 0) wo[t >> 6] = bv;
    __syncthreads();
    int boff = wo[0] + wo[1] + wo[2] + wo[3];
    int i = bid * 256 + t;
    int v = (i < n) ? (int)deg16[i] : 0;
    ls[t] = v;
    __syncthreads();
    for (int d = 1; d < 256; d <<= 1) {
        int u = (t >= d) ? ls[t - d] : 0;
        __syncthreads();
        ls[t] += u;
        __syncthreads();
    }
    int excl = ls[t] - v + boff;
    if (i < n) rowptr[i] = excl;
    if (i == n - 1) rowptr[n] = excl + v;
}

// ---- phase 4: place (no atomics) ----
__global__ void k_place(const int* __restrict__ src, const int* __restrict__ dst,
                        const int* __restrict__ rowptr, const unsigned char* __restrict__ rank,
                        const unsigned char* __restrict__ choff,
                        int* __restrict__ perm, int e, int es) {
    int i = blockIdx.x * 256 + threadIdx.x;
    if (i >= e) return;
    int d = dst[i];
    unsigned int c = (unsigned int)i / (unsigned int)es;
    int slot = rowptr[d] + (int)choff[(size_t)c * NPAD + d] + (int)rank[i];
    perm[slot] = src[i];
}

// ---------------- GEMM: [n,64] @ [64,64], epilogue * dinv[row] ----------------
__global__ __launch_bounds__(256) void k_gemm64(const float* __restrict__ in,
                                                const float* __restrict__ W,
                                                const float* __restrict__ dinv,
                                                float* __restrict__ out, int n) {
    __shared__ float Ws[64 * 64];
    __shared__ float Xs[16 * 64];
    int t = threadIdx.x;
    const float4* W4 = (const float4*)W;
    float4* Ws4 = (float4*)Ws;
#pragma unroll
    for (int i = 0; i < 4; ++i) Ws4[t + 256 * i] = W4[t + 256 * i];
    int row0 = blockIdx.x * 16;
    {
        int r = t >> 4, c4 = t & 15;
        int row = row0 + r;
        float4 v = make_float4(0.f, 0.f, 0.f, 0.f);
        if (row < n) v = ((const float4*)(in + (size_t)row * 64))[c4];
        ((float4*)Xs)[t] = v;
    }
    __syncthreads();
    int c = t & 63, g = t >> 6;
    float a0 = 0.f, a1 = 0.f, a2 = 0.f, a3 = 0.f;
#pragma unroll
    for (int k = 0; k < 64; ++k) {
        float w = Ws[k * 64 + c];
        a0 = fmaf(Xs[g * 64 + k], w, a0);
        a1 = fmaf(Xs[(g + 4) * 64 + k], w, a1);
        a2 = fmaf(Xs[(g + 8) * 64 + k], w, a2);
        a3 = fmaf(Xs[(g + 12) * 64 + k], w, a3);
    }
    int r;
    r = row0 + g;      if (r < n) out[(size_t)r * 64 + c] = a0 * dinv[r];
    r = row0 + g + 4;  if (r < n) out[(size_t)r * 64 + c] = a1 * dinv[r];
    r = row0 + g + 8;  if (r < n) out[(size_t)r * 64 + c] = a2 * dinv[r];
    r = row0 + g + 12; if (r < n) out[(size_t)r * 64 + c] = a3 * dinv[r];
}

// ---------------- GEMM: [n,64] @ [64,4], epilogue * dinv[row] ----------------
__global__ void k_gemm4(const float* __restrict__ in, const float* __restrict__ W,
                        const float* __restrict__ dinv, float* __restrict__ out, int n) {
    __shared__ float Ws[64 * 4];
    int t = threadIdx.x;
    Ws[t] = W[t];
    __syncthreads();
    int row = blockIdx.x * 256 + t;
    if (row >= n) return;
    float a0 = 0.f, a1 = 0.f, a2 = 0.f, a3 = 0.f;
    const float4* xin = (const float4*)(in + (size_t)row * 64);
#pragma unroll
    for (int k4 = 0; k4 < 16; ++k4) {
        float4 x = xin[k4];
        int k = k4 * 4;
        a0 = fmaf(x.x, Ws[k * 4 + 0], a0); a1 = fmaf(x.x, Ws[k * 4 + 1], a1);
        a2 = fmaf(x.x, Ws[k * 4 + 2], a2); a3 = fmaf(x.x, Ws[k * 4 + 3], a3);
        a0 = fmaf(x.y, Ws[k * 4 + 4], a0); a1 = fmaf(x.y, Ws[k * 4 + 5], a1);
        a2 = fmaf(x.y, Ws[k * 4 + 6], a2); a3 = fmaf(x.y, Ws[k * 4 + 7], a3);
        a0 = fmaf(x.z, Ws[k * 4 + 8], a0); a1 = fmaf(x.z, Ws[k * 4 + 9], a1);
        a2 = fmaf(x.z, Ws[k * 4 + 10], a2); a3 = fmaf(x.z, Ws[k * 4 + 11], a3);
        a0 = fmaf(x.w, Ws[k * 4 + 12], a0); a1 = fmaf(x.w, Ws[k * 4 + 13], a1);
        a2 = fmaf(x.w, Ws[k * 4 + 14], a2); a3 = fmaf(x.w, Ws[k * 4 + 15], a3);
    }
    float dv = dinv[row];
    *reinterpret_cast<float4*>(out + (size_t)row * 4) =
        make_float4(a0 * dv, a1 * dv, a2 * dv, a3 * dv);
}

// ---------------- gather 64ch, quad-edge: wave per node, 16 lanes/row, 4 rows/instr ----
// lane = 16*qi + c4: qi-th edge of each quad, channels 4*c4..4*c4+3 (float4).
// 8-quad main loop = 32 edges in flight per wave. Reduce: shfl_xor 16,32.
__device__ __forceinline__ void acc4(float4& a, const float4& u) {
    a.x += u.x; a.y += u.y; a.z += u.z; a.w += u.w;
}

__global__ __launch_bounds__(256) void k_gather64(
        const float* __restrict__ h, const float* __restrict__ dinv,
        const int* __restrict__ rowptr, const int* __restrict__ perm,
        const float* __restrict__ b, float* __restrict__ out, int n, int act) {
    int t = threadIdx.x;
    int v = blockIdx.x * 4 + (t >> 6);
    if (v >= n) return;
    v = __builtin_amdgcn_readfirstlane(v);  // SGPR: rowptr/perm -> scalar loads
    int lane = t & 63;
    int c4 = lane & 15;   // float4 channel group
    int qi = lane >> 4;   // which edge of the quad (0..3)
    const float4* h4 = (const float4*)h;    // row stride 16 float4
    const float4* hl = h4 + c4;
    float4 acc;
    if (qi == 0) acc = hl[(size_t)v * 16];
    else { acc.x = 0.f; acc.y = 0.f; acc.z = 0.f; acc.w = 0.f; }
    int e = rowptr[v], end = rowptr[v + 1];
#define SELQ(j) int sa##j = perm[e + 4*j], sb##j = perm[e + 4*j + 1], \
                    sc##j = perm[e + 4*j + 2], sd##j = perm[e + 4*j + 3]; \
                int s##j = (qi < 2) ? (qi == 0 ? sa##j : sb##j) \
                                    : (qi == 2 ? sc##j : sd##j); \
                float4 q##j = hl[(size_t)s##j * 16]
    for (; e + 32 <= end; e += 32) {
        SELQ(0); SELQ(1); SELQ(2); SELQ(3);
        SELQ(4); SELQ(5); SELQ(6); SELQ(7);
        acc4(acc, q0); acc4(acc, q1); acc4(acc, q2); acc4(acc, q3);
        acc4(acc, q4); acc4(acc, q5); acc4(acc, q6); acc4(acc, q7);
    }
    if (e + 16 <= end) {
        SELQ(0); SELQ(1); SELQ(2); SELQ(3);
        acc4(acc, q0); acc4(acc, q1); acc4(acc, q2); acc4(acc, q3);
        e += 16;
    }
    if (e + 8 <= end) {
        SELQ(0); SELQ(1);
        acc4(acc, q0); acc4(acc, q1);
        e += 8;
    }
    if (e + 4 <= end) {
        SELQ(0);
        acc4(acc, q0);
        e += 4;
    }
#undef SELQ
    // tail 0..3 edges: edge j handled by quad-group qi==j
    int rem = end - e;
    if (rem > 0 && qi < rem) {
        int s = perm[e + qi];
        float4 q = hl[(size_t)s * 16];
        acc4(acc, q);
    }
    // combine the 4 quad-groups
    acc.x += __shfl_xor(acc.x, 16); acc.y += __shfl_xor(acc.y, 16);
    acc.z += __shfl_xor(acc.z, 16); acc.w += __shfl_xor(acc.w, 16);
    acc.x += __shfl_xor(acc.x, 32); acc.y += __shfl_xor(acc.y, 32);
    acc.z += __shfl_xor(acc.z, 32); acc.w += __shfl_xor(acc.w, 32);
    float dv = dinv[v];
    float4 bb = ((const float4*)b)[c4];
    float ox = acc.x * dv + bb.x;
    float oy = acc.y * dv + bb.y;
    float oz = acc.z * dv + bb.z;
    float ow = acc.w * dv + bb.w;
    if (act) {
        ox = ox > 0.f ? ox : ox * NEG_SLOPE;
        oy = oy > 0.f ? oy : oy * NEG_SLOPE;
        oz = oz > 0.f ? oz : oz * NEG_SLOPE;
        ow = ow > 0.f ? ow : ow * NEG_SLOPE;
    }
    if (qi == 0)
        ((float4*)out)[(size_t)v * 16 + c4] = make_float4(ox, oy, oz, ow);
}

// ---------------- gather 4ch: 4 lanes per node, unroll 4 ----------------
__global__ __launch_bounds__(256) void k_gather4(
        const float* __restrict__ h, const float* __restrict__ dinv,
        const int* __restrict__ rowptr, const int* __restrict__ perm,
        const float* __restrict__ b, float* __restrict__ out, int n) {
    int gid = blockIdx.x * 256 + threadIdx.x;
    int c = gid & 3;
    int v = gid >> 2;
    if (v >= n) return;
    const float* hc = h + c;
    float acc = hc[(size_t)v * 4];
    int e = rowptr[v], end = rowptr[v + 1];
    for (; e + 4 <= end; e += 4) {
        float x0 = hc[(size_t)perm[e] * 4];
        float x1 = hc[(size_t)perm[e + 1] * 4];
        float x2 = hc[(size_t)perm[e + 2] * 4];
        float x3 = hc[(size_t)perm[e + 3] * 4];
        acc += (x0 + x1) + (x2 + x3);
    }
    for (; e < end; ++e) acc += hc[(size_t)perm[e] * 4];
    out[(size_t)v * 4 + c] = acc * dinv[v] + b[c];
}

extern "C" void kernel_launch(void* const* d_in, const int* in_sizes, int n_in,
                              void* d_out, int out_size, void* d_ws, size_t ws_size,
                              hipStream_t stream) {
    const float* x  = (const float*)d_in[0];
    const int* ei   = (const int*)d_in[1];
    const float* W0 = (const float*)d_in[2];
    const float* b0 = (const float*)d_in[3];
    const float* W1 = (const float*)d_in[4];
    const float* b1 = (const float*)d_in[5];
    const float* W2 = (const float*)d_in[6];
    const float* b2 = (const float*)d_in[7];
    float* out = (float*)d_out;

    const int N = in_sizes[0] / 64;
    const int E = in_sizes[1] / 2;
    const int* src = ei;
    const int* dst = ei + E;
    const int es = (E + NCHUNK - 1) / NCHUNK;   // edges per chunk

    // workspace layout, 256B-aligned slabs
    char* base = (char*)d_ws;
    size_t off = 0;
    auto alloc = [&](size_t bytes) { size_t o = off; off = (off + bytes + 255) & ~(size_t)255; return o; };
    unsigned int*   histw  = (unsigned int*)(base + alloc((size_t)NCHUNK * NPAD));  // u8[C][NPAD]
    unsigned char*  rank   = (unsigned char*)(base + alloc((size_t)E));
    unsigned short* deg16  = (unsigned short*)(base + alloc((size_t)NPAD * 2));
    float*          dinv   = (float*)(base + alloc((size_t)NPAD * 4));
    int*            rowptr = (int*)(base + alloc((size_t)(NPAD + 1) * 4));
    int*            bsum   = (int*)(base + alloc(1024));
    int*            perm   = (int*)(base + alloc((size_t)E * 4));
    float*          bufA   = (float*)(base + alloc((size_t)N * 64 * 4));
    float*          bufB   = (float*)(base + alloc((size_t)N * 64 * 4));

    const int nb_N = (N + 255) / 256;   // 196
    const int nb_E = (E + 255) / 256;
    const int nb_V = (N + 3) / 4;       // wave per node, 4 per block

    // ---- CSR build + normalization (no global atomics) ----
    k_hist<<<NCHUNK, 1024, NW8 * sizeof(unsigned int), stream>>>(dst, histw, rank, E, es);
    k_chscan<<<NPAD / 256, 256, 0, stream>>>((unsigned char*)histw, dinv, deg16, bsum, N);
    k_scan3<<<nb_N, 256, 0, stream>>>(deg16, bsum, rowptr, N, nb_N);
    k_place<<<nb_E, 256, 0, stream>>>(src, dst, rowptr, rank, (const unsigned char*)histw, perm, E, es);

    // ---- layer 0 ----
    k_gemm64<<<(N + 15) / 16, 256, 0, stream>>>(x, W0, dinv, bufA, N);
    k_gather64<<<nb_V, 256, 0, stream>>>(bufA, dinv, rowptr, perm, b0, bufB, N, 1);

    // ---- layer 1 ----
    k_gemm64<<<(N + 15) / 16, 256, 0, stream>>>(bufB, W1, dinv, bufA, N);
    k_gather64<<<nb_V, 256, 0, stream>>>(bufA, dinv, rowptr, perm, b1, bufB, N, 1);

    // ---- layer 2 (d_out = 4) ----
    k_gemm4<<<nb_N, 256, 0, stream>>>(bufB, W2, dinv, bufA, N);
    k_gather4<<<(N * 4 + 255) / 256, 256, 0, stream>>>(bufA, dinv, rowptr, perm, b2, out, N);
}

// Round 11
// 165.216 us; speedup vs baseline: 1.3468x; 1.1355x over previous
//
#include <hip/hip_runtime.h>
#include <math.h>

#define NEG_SLOPE 0.2f
#define NPAD 50176            // node capacity (multiple of 512)
#define NW8  (NPAD / 4)       // packed u32 cells (4 x u8 counts)
#define NCHUNK 256            // edge chunks == k_hist blocks

// ---- phase 1: per-chunk histogram via LDS atomics (4x u8 packed); emits rank ----
__global__ __launch_bounds__(1024) void k_hist(const int* __restrict__ dst,
                                               unsigned int* __restrict__ histw,
                                               unsigned char* __restrict__ rank,
                                               int e, int es) {
    extern __shared__ unsigned int lcnt[];  // NW8 u32 = 50176 B
    int t = threadIdx.x;
    for (int w = t; w < NW8; w += 1024) lcnt[w] = 0u;
    __syncthreads();
    int beg = blockIdx.x * es;
    int end = min(beg + es, e);
    for (int i = beg + t; i < end; i += 1024) {
        int d = dst[i];
        int sh = (d & 3) << 3;
        unsigned int old = atomicAdd(&lcnt[d >> 2], 1u << sh);
        rank[i] = (unsigned char)((old >> sh) & 0xffu);
    }
    __syncthreads();
    unsigned int* out = histw + (size_t)blockIdx.x * NW8;
    for (int w = t; w < NW8; w += 1024) out[w] = lcnt[w];
}

// ---- phase 2: per-node exclusive scan over chunks (in place, u8), deg/dinv/bsum ----
__global__ __launch_bounds__(256) void k_chscan(unsigned char* __restrict__ hist8,
                                                float* __restrict__ dinv,
                                                unsigned short* __restrict__ deg16,
                                                int* __restrict__ bsum, int n) {
    int t = threadIdx.x;
    int i = blockIdx.x * 256 + t;          // grid covers NPAD exactly
    unsigned char* p = hist8 + i;
    unsigned int run = 0;
    for (int c = 0; c < NCHUNK; c += 8) {
        size_t b = (size_t)c * NPAD;
        unsigned char v0 = p[b];
        unsigned char v1 = p[b + (size_t)1 * NPAD];
        unsigned char v2 = p[b + (size_t)2 * NPAD];
        unsigned char v3 = p[b + (size_t)3 * NPAD];
        unsigned char v4 = p[b + (size_t)4 * NPAD];
        unsigned char v5 = p[b + (size_t)5 * NPAD];
        unsigned char v6 = p[b + (size_t)6 * NPAD];
        unsigned char v7 = p[b + (size_t)7 * NPAD];
        unsigned int e0 = run;
        unsigned int e1 = e0 + v0;
        unsigned int e2 = e1 + v1;
        unsigned int e3 = e2 + v2;
        unsigned int e4 = e3 + v3;
        unsigned int e5 = e4 + v4;
        unsigned int e6 = e5 + v5;
        unsigned int e7 = e6 + v6;
        run = e7 + v7;
        p[b] = (unsigned char)e0;
        p[b + (size_t)1 * NPAD] = (unsigned char)e1;
        p[b + (size_t)2 * NPAD] = (unsigned char)e2;
        p[b + (size_t)3 * NPAD] = (unsigned char)e3;
        p[b + (size_t)4 * NPAD] = (unsigned char)e4;
        p[b + (size_t)5 * NPAD] = (unsigned char)e5;
        p[b + (size_t)6 * NPAD] = (unsigned char)e6;
        p[b + (size_t)7 * NPAD] = (unsigned char)e7;
    }
    int deg = (int)run;
    if (i < n) dinv[i] = rsqrtf((float)(deg + 1));  // +1 self-loop
    deg16[i] = (unsigned short)deg;                 // zero beyond n
    int s = deg;
    for (int d = 1; d < 64; d <<= 1) s += __shfl_down(s, d);
    __shared__ int ws[4];
    if ((t & 63) == 0) ws[t >> 6] = s;
    __syncthreads();
    if (t == 0) bsum[blockIdx.x] = ws[0] + ws[1] + ws[2] + ws[3];
}

// ---- phase 3: rowptr = global exclusive scan (block prefix of bsum + local scan) ----
__global__ __launch_bounds__(256) void k_scan3(const unsigned short* __restrict__ deg16,
                                               const int* __restrict__ bsum,
                                               int* __restrict__ rowptr, int n, int nb) {
    __shared__ int ls[256];
    __shared__ int wo[4];
    int t = threadIdx.x;
    int bid = blockIdx.x;
    int bv = (t < bid && t < nb) ? bsum[t] : 0;
    for (int d = 1; d < 64; d <<= 1) bv += __shfl_down(bv, d);
    if ((t & 63) == 0) wo[t >> 6] = bv;
    __syncthreads();
    int boff = wo[0] + wo[1] + wo[2] + wo[3];
    int i = bid * 256 + t;
    int v = (i < n) ? (int)deg16[i] : 0;
    ls[t] = v;
    __syncthreads();
    for (int d = 1; d < 256; d <<= 1) {
        int u = (t >= d) ? ls[t - d] : 0;
        __syncthreads();
        ls[t] += u;
        __syncthreads();
    }
    int excl = ls[t] - v + boff;
    if (i < n) rowptr[i] = excl;
    if (i == n - 1) rowptr[n] = excl + v;
}

// ---- phase 4: place (no atomics) ----
__global__ void k_place(const int* __restrict__ src, const int* __restrict__ dst,
                        const int* __restrict__ rowptr, const unsigned char* __restrict__ rank,
                        const unsigned char* __restrict__ choff,
                        int* __restrict__ perm, int e, int es) {
    int i = blockIdx.x * 256 + threadIdx.x;
    if (i >= e) return;
    int d = dst[i];
    unsigned int c = (unsigned int)i / (unsigned int)es;
    int slot = rowptr[d] + (int)choff[(size_t)c * NPAD + d] + (int)rank[i];
    perm[slot] = src[i];
}

// ---------------- GEMM: [n,64] @ [64,64], epilogue * dinv[row], fp16 out ----------------
__global__ __launch_bounds__(256) void k_gemm64(const float* __restrict__ in,
                                                const float* __restrict__ W,
                                                const float* __restrict__ dinv,
                                                _Float16* __restrict__ out, int n) {
    __shared__ float Ws[64 * 64];
    __shared__ float Xs[16 * 64];
    int t = threadIdx.x;
    const float4* W4 = (const float4*)W;
    float4* Ws4 = (float4*)Ws;
#pragma unroll
    for (int i = 0; i < 4; ++i) Ws4[t + 256 * i] = W4[t + 256 * i];
    int row0 = blockIdx.x * 16;
    {
        int r = t >> 4, c4 = t & 15;
        int row = row0 + r;
        float4 v = make_float4(0.f, 0.f, 0.f, 0.f);
        if (row < n) v = ((const float4*)(in + (size_t)row * 64))[c4];
        ((float4*)Xs)[t] = v;
    }
    __syncthreads();
    int c = t & 63, g = t >> 6;
    float a0 = 0.f, a1 = 0.f, a2 = 0.f, a3 = 0.f;
#pragma unroll
    for (int k = 0; k < 64; ++k) {
        float w = Ws[k * 64 + c];
        a0 = fmaf(Xs[g * 64 + k], w, a0);
        a1 = fmaf(Xs[(g + 4) * 64 + k], w, a1);
        a2 = fmaf(Xs[(g + 8) * 64 + k], w, a2);
        a3 = fmaf(Xs[(g + 12) * 64 + k], w, a3);
    }
    int r;
    r = row0 + g;      if (r < n) out[(size_t)r * 64 + c] = (_Float16)(a0 * dinv[r]);
    r = row0 + g + 4;  if (r < n) out[(size_t)r * 64 + c] = (_Float16)(a1 * dinv[r]);
    r = row0 + g + 8;  if (r < n) out[(size_t)r * 64 + c] = (_Float16)(a2 * dinv[r]);
    r = row0 + g + 12; if (r < n) out[(size_t)r * 64 + c] = (_Float16)(a3 * dinv[r]);
}

// ---------------- GEMM: [n,64] @ [64,4], epilogue * dinv[row] (fp32 in/out) ----------------
__global__ void k_gemm4(const float* __restrict__ in, const float* __restrict__ W,
                        const float* __restrict__ dinv, float* __restrict__ out, int n) {
    __shared__ float Ws[64 * 4];
    int t = threadIdx.x;
    Ws[t] = W[t];
    __syncthreads();
    int row = blockIdx.x * 256 + t;
    if (row >= n) return;
    float a0 = 0.f, a1 = 0.f, a2 = 0.f, a3 = 0.f;
    const float4* xin = (const float4*)(in + (size_t)row * 64);
#pragma unroll
    for (int k4 = 0; k4 < 16; ++k4) {
        float4 x = xin[k4];
        int k = k4 * 4;
        a0 = fmaf(x.x, Ws[k * 4 + 0], a0); a1 = fmaf(x.x, Ws[k * 4 + 1], a1);
        a2 = fmaf(x.x, Ws[k * 4 + 2], a2); a3 = fmaf(x.x, Ws[k * 4 + 3], a3);
        a0 = fmaf(x.y, Ws[k * 4 + 4], a0); a1 = fmaf(x.y, Ws[k * 4 + 5], a1);
        a2 = fmaf(x.y, Ws[k * 4 + 6], a2); a3 = fmaf(x.y, Ws[k * 4 + 7], a3);
        a0 = fmaf(x.z, Ws[k * 4 + 8], a0); a1 = fmaf(x.z, Ws[k * 4 + 9], a1);
        a2 = fmaf(x.z, Ws[k * 4 + 10], a2); a3 = fmaf(x.z, Ws[k * 4 + 11], a3);
        a0 = fmaf(x.w, Ws[k * 4 + 12], a0); a1 = fmaf(x.w, Ws[k * 4 + 13], a1);
        a2 = fmaf(x.w, Ws[k * 4 + 14], a2); a3 = fmaf(x.w, Ws[k * 4 + 15], a3);
    }
    float dv = dinv[row];
    *reinterpret_cast<float4*>(out + (size_t)row * 4) =
        make_float4(a0 * dv, a1 * dv, a2 * dv, a3 * dv);
}

// ---------------- gather 64ch: fp16 rows (128B), wave per node, lane=channel, unroll 16 ----
__global__ __launch_bounds__(256) void k_gather64(
        const _Float16* __restrict__ h, const float* __restrict__ dinv,
        const int* __restrict__ rowptr, const int* __restrict__ perm,
        const float* __restrict__ b, float* __restrict__ out, int n, int act) {
    int t = threadIdx.x;
    int v = blockIdx.x * 4 + (t >> 6);
    if (v >= n) return;
    v = __builtin_amdgcn_readfirstlane(v);  // SGPR: rowptr/perm -> scalar loads
    int lane = t & 63;
    const _Float16* hl = h + lane;
    float acc = (float)hl[(size_t)v * 64];
    int e = rowptr[v], end = rowptr[v + 1];
#define LOADK(j) float x##j = (float)hl[(size_t)perm[e + j] * 64]
    for (; e + 16 <= end; e += 16) {
        LOADK(0); LOADK(1); LOADK(2); LOADK(3);
        LOADK(4); LOADK(5); LOADK(6); LOADK(7);
        LOADK(8); LOADK(9); LOADK(10); LOADK(11);
        LOADK(12); LOADK(13); LOADK(14); LOADK(15);
        acc += (((x0 + x1) + (x2 + x3)) + ((x4 + x5) + (x6 + x7)))
             + (((x8 + x9) + (x10 + x11)) + ((x12 + x13) + (x14 + x15)));
    }
    if (e + 8 <= end) {
        LOADK(0); LOADK(1); LOADK(2); LOADK(3);
        LOADK(4); LOADK(5); LOADK(6); LOADK(7);
        acc += ((x0 + x1) + (x2 + x3)) + ((x4 + x5) + (x6 + x7));
        e += 8;
    }
    if (e + 4 <= end) {
        LOADK(0); LOADK(1); LOADK(2); LOADK(3);
        acc += (x0 + x1) + (x2 + x3);
        e += 4;
    }
    if (e + 2 <= end) {
        LOADK(0); LOADK(1);
        acc += x0 + x1;
        e += 2;
    }
    if (e < end) acc += (float)hl[(size_t)perm[e] * 64];
#undef LOADK
    acc = acc * dinv[v] + b[lane];
    if (act) acc = acc > 0.0f ? acc : acc * NEG_SLOPE;
    out[(size_t)v * 64 + lane] = acc;
}

// ---------------- gather 4ch: 4 lanes per node, fp32, unroll 4 ----------------
__global__ __launch_bounds__(256) void k_gather4(
        const float* __restrict__ h, const float* __restrict__ dinv,
        const int* __restrict__ rowptr, const int* __restrict__ perm,
        const float* __restrict__ b, float* __restrict__ out, int n) {
    int gid = blockIdx.x * 256 + threadIdx.x;
    int c = gid & 3;
    int v = gid >> 2;
    if (v >= n) return;
    const float* hc = h + c;
    float acc = hc[(size_t)v * 4];
    int e = rowptr[v], end = rowptr[v + 1];
    for (; e + 4 <= end; e += 4) {
        float x0 = hc[(size_t)perm[e] * 4];
        float x1 = hc[(size_t)perm[e + 1] * 4];
        float x2 = hc[(size_t)perm[e + 2] * 4];
        float x3 = hc[(size_t)perm[e + 3] * 4];
        acc += (x0 + x1) + (x2 + x3);
    }
    for (; e < end; ++e) acc += hc[(size_t)perm[e] * 4];
    out[(size_t)v * 4 + c] = acc * dinv[v] + b[c];
}

extern "C" void kernel_launch(void* const* d_in, const int* in_sizes, int n_in,
                              void* d_out, int out_size, void* d_ws, size_t ws_size,
                              hipStream_t stream) {
    const float* x  = (const float*)d_in[0];
    const int* ei   = (const int*)d_in[1];
    const float* W0 = (const float*)d_in[2];
    const float* b0 = (const float*)d_in[3];
    const float* W1 = (const float*)d_in[4];
    const float* b1 = (const float*)d_in[5];
    const float* W2 = (const float*)d_in[6];
    const float* b2 = (const float*)d_in[7];
    float* out = (float*)d_out;

    const int N = in_sizes[0] / 64;
    const int E = in_sizes[1] / 2;
    const int* src = ei;
    const int* dst = ei + E;
    const int es = (E + NCHUNK - 1) / NCHUNK;   // edges per chunk

    // workspace layout, 256B-aligned slabs
    char* base = (char*)d_ws;
    size_t off = 0;
    auto alloc = [&](size_t bytes) { size_t o = off; off = (off + bytes + 255) & ~(size_t)255; return o; };
    unsigned int*   histw  = (unsigned int*)(base + alloc((size_t)NCHUNK * NPAD));  // u8[C][NPAD]
    unsigned char*  rank   = (unsigned char*)(base + alloc((size_t)E));
    unsigned short* deg16  = (unsigned short*)(base + alloc((size_t)NPAD * 2));
    float*          dinv   = (float*)(base + alloc((size_t)NPAD * 4));
    int*            rowptr = (int*)(base + alloc((size_t)(NPAD + 1) * 4));
    int*            bsum   = (int*)(base + alloc(1024));
    int*            perm   = (int*)(base + alloc((size_t)E * 4));
    _Float16*       bufH   = (_Float16*)(base + alloc((size_t)N * 64 * 2));  // fp16 gather operand
    float*          bufB   = (float*)(base + alloc((size_t)N * 64 * 4));     // fp32 act output
    float*          bufD   = (float*)(base + alloc((size_t)N * 4 * 4));      // fp32 4-wide

    const int nb_N = (N + 255) / 256;   // 196
    const int nb_E = (E + 255) / 256;
    const int nb_V = (N + 3) / 4;       // wave per node, 4 per block

    // ---- CSR build + normalization (no global atomics) ----
    k_hist<<<NCHUNK, 1024, NW8 * sizeof(unsigned int), stream>>>(dst, histw, rank, E, es);
    k_chscan<<<NPAD / 256, 256, 0, stream>>>((unsigned char*)histw, dinv, deg16, bsum, N);
    k_scan3<<<nb_N, 256, 0, stream>>>(deg16, bsum, rowptr, N, nb_N);
    k_place<<<nb_E, 256, 0, stream>>>(src, dst, rowptr, rank, (const unsigned char*)histw, perm, E, es);

    // ---- layer 0 ----
    k_gemm64<<<(N + 15) / 16, 256, 0, stream>>>(x, W0, dinv, bufH, N);
    k_gather64<<<nb_V, 256, 0, stream>>>(bufH, dinv, rowptr, perm, b0, bufB, N, 1);

    // ---- layer 1 ----
    k_gemm64<<<(N + 15) / 16, 256, 0, stream>>>(bufB, W1, dinv, bufH, N);
    k_gather64<<<nb_V, 256, 0, stream>>>(bufH, dinv, rowptr, perm, b1, bufB, N, 1);

    // ---- layer 2 (d_out = 4) ----
    k_gemm4<<<nb_N, 256, 0, stream>>>(bufB, W2, dinv, bufD, N);
    k_gather4<<<(N * 4 + 255) / 256, 256, 0, stream>>>(bufD, dinv, rowptr, perm, b2, out, N);
}